// Round 1
// baseline (2323.087 us; speedup 1.0000x reference)
//
#include <hip/hip_runtime.h>

// ---------------- problem constants ----------------
constexpr int kB = 2, kT = 1024, kD = 1024, kDI = 2048, kH = 16, kE = 8, kF = 2048;
constexpr int kBT = kB * kT;
constexpr float kEPS = 1.1920929e-07f;

// ---------------- workspace layout (float units) ----------------
constexpr size_t MF = 1024ull * 1024ull;
constexpr size_t F_H      = 0;                 // 2MF   (dead after fuse gemm)
constexpr size_t F_HH     = 0;                 // 9MF   (MoE phase reuse)
constexpr size_t F_XIN    = 2*MF;              // 4MF
constexpr size_t F_EXPA   = 6*MF;              // 32768
constexpr size_t F_CB     = 6*MF + 32768;      // 32768
constexpr size_t F_CC     = 6*MF + 65536;      // 32768
constexpr size_t F_P      = 7*MF;              // 1MF
constexpr size_t F_Q      = 8*MF;              // 1MF
constexpr size_t F_S0     = 9*MF;              // 1MF
constexpr size_t F_YS     = 10*MF;             // 4MF
constexpr size_t F_SSMO   = 14*MF;             // 2MF
constexpr size_t F_ATTNO  = 16*MF;             // 2MF
constexpr size_t F_H2     = 18*MF;             // 2MF
constexpr size_t F_NORMED = 20*MF;             // 4MF (dead before q)
constexpr size_t F_QB     = 20*MF;             // 2MF
constexpr size_t F_KB     = 22*MF;             // 2MF
constexpr size_t F_VB     = 24*MF;             // 2MF
constexpr size_t F_LAT    = 26*MF;             // 0.5MF
constexpr size_t F_CTX    = 26*MF + MF/2;      // 2MF
constexpr size_t F_FUSE   = 28*MF + MF/2;      // 2MF (ends 30.5MF)
constexpr size_t F_XZ     = 31*MF;             // 8MF (dead after glu)
constexpr size_t F_SCORES = 31*MF;             // 16MF per-b (dead after PV)
constexpr size_t F_QG8    = 31*MF;             // int8 16MB
constexpr size_t F_QU8    = 35*MF;             // int8 16MB
constexpr size_t F_QD8    = 39*MF;             // int8 16MB (ends 43MF)
constexpr size_t F_MISC   = 47*MF;
constexpr size_t P_PART   = F_MISC;            // 3*1024
constexpr size_t P_THRESH = F_MISC + 3072;     // 3
constexpr size_t P_PROBS  = F_MISC + 3080;     // 8
constexpr size_t I_COUNTS = F_MISC + 3088;     // 8
constexpr size_t I_OFFS   = F_MISC + 3096;     // 9
constexpr size_t I_CURSOR = F_MISC + 3105;     // 8
constexpr size_t I_NTILES = F_MISC + 3113;     // 1
constexpr size_t I_TILEE  = F_MISC + 3114;     // 80
constexpr size_t I_TILEB  = F_MISC + 3194;     // 80
constexpr size_t I_TOPI   = F_MISC + 3274;     // 4096
constexpr size_t P_TOPW   = F_MISC + 7370;     // 4096
constexpr size_t I_PAIRT  = F_MISC + 11466;    // 8192
constexpr size_t P_PAIRW  = F_MISC + 19658;    // 8192
constexpr size_t WS_FLOATS = F_MISC + 32768;

__device__ __forceinline__ float sigmoidf_(float v) { return 1.f / (1.f + expf(-v)); }

// ---------------- misc small kernels ----------------
__global__ void zero_k(float* p, int n) {
    int i = blockIdx.x * blockDim.x + threadIdx.x;
    if (i < n) p[i] = 0.f;
}

__global__ __launch_bounds__(256) void rmsnorm_k(const float* __restrict__ x,
                                                 const float* __restrict__ w,
                                                 float* __restrict__ y, int C) {
    int row = blockIdx.x, tid = threadIdx.x;
    const float* xr = x + (size_t)row * C;
    float* yr = y + (size_t)row * C;
    float ss = 0.f;
    for (int c = tid * 4; c < C; c += 1024) {
        float4 v = *(const float4*)(xr + c);
        ss += v.x*v.x + v.y*v.y + v.z*v.z + v.w*v.w;
    }
    for (int off = 32; off; off >>= 1) ss += __shfl_xor(ss, off);
    __shared__ float red[4];
    if ((tid & 63) == 0) red[tid >> 6] = ss;
    __syncthreads();
    ss = red[0] + red[1] + red[2] + red[3];
    float r = rsqrtf(ss / C + kEPS);
    for (int c = tid * 4; c < C; c += 1024) {
        float4 v = *(const float4*)(xr + c);
        float4 g = *(const float4*)(w + c);
        v.x *= r * g.x; v.y *= r * g.y; v.z *= r * g.z; v.w *= r * g.w;
        *(float4*)(yr + c) = v;
    }
}

// ---------------- generic f32 GEMMs: C[M,N] = A[M,K] * B^T (B is [N,K]) ----------------
__global__ __launch_bounds__(256) void gemm_nt(const float* __restrict__ A,
                                               const float* __restrict__ Bm,
                                               float* __restrict__ C,
                                               int K, int lda, int ldb, int ldc,
                                               int bh, long sAb, long sAh, long sBb, long sBh,
                                               long sCb, long sCh) {
    int z = blockIdx.z, zb = z / bh, zh = z - zb * bh;
    A  += (size_t)zb * sAb + (size_t)zh * sAh;
    Bm += (size_t)zb * sBb + (size_t)zh * sBh;
    C  += (size_t)zb * sCb + (size_t)zh * sCh;
    __shared__ __align__(16) float As[16][68], Bs[16][68];
    int tid = threadIdx.x;
    int tx = tid & 15, ty = tid >> 4;
    int m0 = blockIdx.y << 6, n0 = blockIdx.x << 6;
    int lr = tid >> 2, lk = (tid & 3) << 2;
    const float* Ap = A + (size_t)(m0 + lr) * lda + lk;
    const float* Bp = Bm + (size_t)(n0 + lr) * ldb + lk;
    float acc[4][4] = {};
    for (int kt = 0; kt < K; kt += 16) {
        float4 a4 = *(const float4*)(Ap + kt);
        float4 b4 = *(const float4*)(Bp + kt);
        __syncthreads();
        As[lk+0][lr] = a4.x; As[lk+1][lr] = a4.y; As[lk+2][lr] = a4.z; As[lk+3][lr] = a4.w;
        Bs[lk+0][lr] = b4.x; Bs[lk+1][lr] = b4.y; Bs[lk+2][lr] = b4.z; Bs[lk+3][lr] = b4.w;
        __syncthreads();
#pragma unroll
        for (int kk = 0; kk < 16; kk++) {
            float4 av = *(const float4*)&As[kk][ty << 2];
            float4 bv = *(const float4*)&Bs[kk][tx << 2];
            float a_[4] = {av.x, av.y, av.z, av.w};
            float b_[4] = {bv.x, bv.y, bv.z, bv.w};
#pragma unroll
            for (int i = 0; i < 4; i++)
#pragma unroll
                for (int j = 0; j < 4; j++) acc[i][j] = fmaf(a_[i], b_[j], acc[i][j]);
        }
    }
#pragma unroll
    for (int i = 0; i < 4; i++) {
        float4 o = make_float4(acc[i][0], acc[i][1], acc[i][2], acc[i][3]);
        *(float4*)(C + (size_t)(m0 + (ty << 2) + i) * ldc + n0 + (tx << 2)) = o;
    }
}

// C[M,N] = A[M,K] * B[K,N]  (B row-major K x N)
__global__ __launch_bounds__(256) void gemm_nn(const float* __restrict__ A,
                                               const float* __restrict__ Bm,
                                               float* __restrict__ C,
                                               int K, int lda, int ldb, int ldc,
                                               int bh, long sAb, long sAh, long sBb, long sBh,
                                               long sCb, long sCh) {
    int z = blockIdx.z, zb = z / bh, zh = z - zb * bh;
    A  += (size_t)zb * sAb + (size_t)zh * sAh;
    Bm += (size_t)zb * sBb + (size_t)zh * sBh;
    C  += (size_t)zb * sCb + (size_t)zh * sCh;
    __shared__ __align__(16) float As[16][68], Bs[16][68];
    int tid = threadIdx.x;
    int tx = tid & 15, ty = tid >> 4;
    int m0 = blockIdx.y << 6, n0 = blockIdx.x << 6;
    int lr = tid >> 2, lk = (tid & 3) << 2;     // A staging
    int bk = tid >> 4, bn = (tid & 15) << 2;    // B staging
    const float* Ap = A + (size_t)(m0 + lr) * lda + lk;
    const float* Bp = Bm + (size_t)bk * ldb + n0 + bn;
    float acc[4][4] = {};
    for (int kt = 0; kt < K; kt += 16) {
        float4 a4 = *(const float4*)(Ap + kt);
        float4 b4 = *(const float4*)(Bp + (size_t)kt * ldb);
        __syncthreads();
        As[lk+0][lr] = a4.x; As[lk+1][lr] = a4.y; As[lk+2][lr] = a4.z; As[lk+3][lr] = a4.w;
        *(float4*)&Bs[bk][bn] = b4;
        __syncthreads();
#pragma unroll
        for (int kk = 0; kk < 16; kk++) {
            float4 av = *(const float4*)&As[kk][ty << 2];
            float4 bv = *(const float4*)&Bs[kk][tx << 2];
            float a_[4] = {av.x, av.y, av.z, av.w};
            float b_[4] = {bv.x, bv.y, bv.z, bv.w};
#pragma unroll
            for (int i = 0; i < 4; i++)
#pragma unroll
                for (int j = 0; j < 4; j++) acc[i][j] = fmaf(a_[i], b_[j], acc[i][j]);
        }
    }
#pragma unroll
    for (int i = 0; i < 4; i++) {
        float4 o = make_float4(acc[i][0], acc[i][1], acc[i][2], acc[i][3]);
        *(float4*)(C + (size_t)(m0 + (ty << 2) + i) * ldc + n0 + (tx << 2)) = o;
    }
}

// ---------------- SSM ----------------
__global__ void glu_k(const float* __restrict__ xz, float* __restrict__ xin) {
    int g = blockIdx.x * blockDim.x + threadIdx.x;
    if (g >= kBT * kDI / 4) return;
    int t = g >> 9, c4 = (g & 511) << 2;
    const float* row = xz + (size_t)t * 2 * kDI;
    float4 a = *(const float4*)(row + c4);
    float4 b = *(const float4*)(row + kDI + c4);
    float4 o;
    o.x = a.x * sigmoidf_(a.x) * sigmoidf_(b.x);
    o.y = a.y * sigmoidf_(a.y) * sigmoidf_(b.y);
    o.z = a.z * sigmoidf_(a.z) * sigmoidf_(b.z);
    o.w = a.w * sigmoidf_(a.w) * sigmoidf_(b.w);
    *(float4*)(xin + (size_t)t * kDI + c4) = o;
}

// per token: 48 dots of length 2048 -> expA / B / C coefficients
__global__ __launch_bounds__(256) void projabc_k(const float* __restrict__ xin,
                                                 const float* __restrict__ Aw,
                                                 const float* __restrict__ Bw,
                                                 const float* __restrict__ Cw,
                                                 float* __restrict__ expA,
                                                 float* __restrict__ Bc,
                                                 float* __restrict__ Cc) {
    int t = blockIdx.x;
    int wv = threadIdx.x >> 6, lane = threadIdx.x & 63;
    const float* Wp[12];
#pragma unroll
    for (int j = 0; j < 12; j++) {
        int o = wv * 12 + j;
        Wp[j] = (o < 16) ? (Aw + (size_t)o * kDI)
              : (o < 32) ? (Bw + (size_t)(o - 16) * kDI)
                         : (Cw + (size_t)(o - 32) * kDI);
    }
    float part[12] = {};
    const float* xr = xin + (size_t)t * kDI;
    for (int i = 0; i < kDI / 64; i++) {
        int d = lane + (i << 6);
        float xv = xr[d];
#pragma unroll
        for (int j = 0; j < 12; j++) part[j] = fmaf(xv, Wp[j][d], part[j]);
    }
#pragma unroll
    for (int j = 0; j < 12; j++)
        for (int off = 32; off; off >>= 1) part[j] += __shfl_xor(part[j], off);
    if (lane == 0) {
#pragma unroll
        for (int j = 0; j < 12; j++) {
            int o = wv * 12 + j;
            float v = part[j];
            if (o < 16) {
                float zc = fminf(fmaxf(v, -5.f), 0.f);
                expA[(size_t)t * 16 + o] = expf(-expf(zc));
            } else if (o < 32) Bc[(size_t)t * 16 + (o - 16)] = v;
            else Cc[(size_t)t * 16 + (o - 32)] = v;
        }
    }
}

// chunked scan: 16 chunks of 64 steps. pass1: per-chunk (P = prod expA, Q = run from 0)
__global__ __launch_bounds__(256) void scan_pass1(const float* __restrict__ xin,
                                                  const float* __restrict__ expA,
                                                  const float* __restrict__ Bc,
                                                  float* __restrict__ Pv, float* __restrict__ Qv) {
    int c = blockIdx.y;
    int ch = blockIdx.x * 256 + threadIdx.x;
    int b = ch >> 11, d = ch & (kDI - 1);
    __shared__ __align__(16) float sE[1024], sB[1024];
    size_t cbase = ((size_t)b * kT + c * 64) * 16;
    *(float4*)(sE + threadIdx.x * 4) = *(const float4*)(expA + cbase + threadIdx.x * 4);
    *(float4*)(sB + threadIdx.x * 4) = *(const float4*)(Bc + cbase + threadIdx.x * 4);
    __syncthreads();
    float s[16], p[16];
#pragma unroll
    for (int n = 0; n < 16; n++) { s[n] = 0.f; p[n] = 1.f; }
    const float* xp = xin + ((size_t)b * kT + c * 64) * kDI + d;
    for (int tl = 0; tl < 64; tl++) {
        float xv = xp[(size_t)tl * kDI];
        const float* e = sE + tl * 16;
        const float* bb = sB + tl * 16;
#pragma unroll
        for (int n = 0; n < 16; n++) {
            float ev = e[n];
            s[n] = s[n] * ev + xv * bb[n];
            p[n] *= ev;
        }
    }
    size_t ob = ((size_t)c * 4096 + ch) * 16;
#pragma unroll
    for (int q = 0; q < 16; q += 4) {
        *(float4*)(Pv + ob + q) = make_float4(p[q], p[q+1], p[q+2], p[q+3]);
        *(float4*)(Qv + ob + q) = make_float4(s[q], s[q+1], s[q+2], s[q+3]);
    }
}

__global__ __launch_bounds__(256) void scan_combine(const float* __restrict__ Pv,
                                                    const float* __restrict__ Qv,
                                                    float* __restrict__ S0) {
    int ch = blockIdx.x * 256 + threadIdx.x;
    float s[16] = {};
    for (int c = 0; c < 16; c++) {
        size_t base = ((size_t)c * 4096 + ch) * 16;
#pragma unroll
        for (int q = 0; q < 16; q += 4)
            *(float4*)(S0 + base + q) = make_float4(s[q], s[q+1], s[q+2], s[q+3]);
#pragma unroll
        for (int q = 0; q < 16; q += 4) {
            float4 pv = *(const float4*)(Pv + base + q);
            float4 qv = *(const float4*)(Qv + base + q);
            s[q+0] = s[q+0] * pv.x + qv.x;
            s[q+1] = s[q+1] * pv.y + qv.y;
            s[q+2] = s[q+2] * pv.z + qv.z;
            s[q+3] = s[q+3] * pv.w + qv.w;
        }
    }
}

__global__ __launch_bounds__(256) void scan_pass2(const float* __restrict__ xin,
                                                  const float* __restrict__ expA,
                                                  const float* __restrict__ Bc,
                                                  const float* __restrict__ Cc,
                                                  const float* __restrict__ S0,
                                                  float* __restrict__ ys) {
    int c = blockIdx.y;
    int ch = blockIdx.x * 256 + threadIdx.x;
    int b = ch >> 11, d = ch & (kDI - 1);
    __shared__ __align__(16) float sE[1024], sB[1024], sC[1024];
    size_t cbase = ((size_t)b * kT + c * 64) * 16;
    *(float4*)(sE + threadIdx.x * 4) = *(const float4*)(expA + cbase + threadIdx.x * 4);
    *(float4*)(sB + threadIdx.x * 4) = *(const float4*)(Bc + cbase + threadIdx.x * 4);
    *(float4*)(sC + threadIdx.x * 4) = *(const float4*)(Cc + cbase + threadIdx.x * 4);
    __syncthreads();
    float s[16];
    size_t sb = ((size_t)c * 4096 + ch) * 16;
#pragma unroll
    for (int q = 0; q < 16; q += 4) {
        float4 v = *(const float4*)(S0 + sb + q);
        s[q] = v.x; s[q+1] = v.y; s[q+2] = v.z; s[q+3] = v.w;
    }
    const float* xp = xin + ((size_t)b * kT + c * 64) * kDI + d;
    float* yp = ys + ((size_t)b * kT + c * 64) * kDI + d;
    for (int tl = 0; tl < 64; tl++) {
        float xv = xp[(size_t)tl * kDI];
        const float* e = sE + tl * 16;
        const float* bb = sB + tl * 16;
        const float* cc = sC + tl * 16;
        float y = 0.f;
#pragma unroll
        for (int n = 0; n < 16; n++) {
            float ev = e[n];
            s[n] = s[n] * ev + xv * bb[n];
            y = fmaf(s[n], cc[n], y);
        }
        yp[(size_t)tl * kDI] = y;
    }
}

// ---------------- attention softmax (rows of 1024, scale 1/8) ----------------
__global__ __launch_bounds__(256) void softmax_rows(float* __restrict__ S) {
    size_t row = blockIdx.x;
    float* r = S + row * 1024;
    int tid = threadIdx.x;
    float4 v = *(const float4*)(r + tid * 4);
    v.x *= 0.125f; v.y *= 0.125f; v.z *= 0.125f; v.w *= 0.125f;
    float mx = fmaxf(fmaxf(v.x, v.y), fmaxf(v.z, v.w));
    for (int off = 32; off; off >>= 1) mx = fmaxf(mx, __shfl_xor(mx, off));
    __shared__ float red[4];
    if ((tid & 63) == 0) red[tid >> 6] = mx;
    __syncthreads();
    mx = fmaxf(fmaxf(red[0], red[1]), fmaxf(red[2], red[3]));
    v.x = expf(v.x - mx); v.y = expf(v.y - mx); v.z = expf(v.z - mx); v.w = expf(v.w - mx);
    float sm = v.x + v.y + v.z + v.w;
    for (int off = 32; off; off >>= 1) sm += __shfl_xor(sm, off);
    __syncthreads();
    if ((tid & 63) == 0) red[tid >> 6] = sm;
    __syncthreads();
    sm = red[0] + red[1] + red[2] + red[3];
    float inv = 1.f / sm;
    v.x *= inv; v.y *= inv; v.z *= inv; v.w *= inv;
    *(float4*)(r + tid * 4) = v;
}

// ---------------- gated fuse ----------------
__global__ void fuse_k(const float* __restrict__ x, const float* __restrict__ fl,
                       const float* __restrict__ ssm, const float* __restrict__ attn,
                       float* __restrict__ out) {
    int g = blockIdx.x * blockDim.x + threadIdx.x;
    if (g >= kBT * kD / 4) return;
    float4 xv = ((const float4*)x)[g];
    float4 fv = ((const float4*)fl)[g];
    float4 sv = ((const float4*)ssm)[g];
    float4 av = ((const float4*)attn)[g];
    float4 o;
    float gt;
    gt = sigmoidf_(fv.x); o.x = xv.x + gt * sv.x + (1.f - gt) * av.x;
    gt = sigmoidf_(fv.y); o.y = xv.y + gt * sv.y + (1.f - gt) * av.y;
    gt = sigmoidf_(fv.z); o.z = xv.z + gt * sv.z + (1.f - gt) * av.z;
    gt = sigmoidf_(fv.w); o.w = xv.w + gt * sv.w + (1.f - gt) * av.w;
    ((float4*)out)[g] = o;
}

// ---------------- ternary quantization ----------------
__global__ __launch_bounds__(256) void absmean_partial(const float* __restrict__ w,
                                                       float* __restrict__ part) {
    size_t i0 = ((size_t)blockIdx.x * 256 + threadIdx.x) * 4;
    float s = 0.f;
    for (int it = 0; it < 16; it++) {
        float4 v = *(const float4*)(w + i0 + (size_t)it * 1048576);
        s += fabsf(v.x) + fabsf(v.y) + fabsf(v.z) + fabsf(v.w);
    }
    for (int off = 32; off; off >>= 1) s += __shfl_xor(s, off);
    __shared__ float red[4];
    if ((threadIdx.x & 63) == 0) red[threadIdx.x >> 6] = s;
    __syncthreads();
    if (threadIdx.x == 0) part[blockIdx.x] = red[0] + red[1] + red[2] + red[3];
}

__global__ __launch_bounds__(256) void thresh_k(const float* __restrict__ part,
                                                float* __restrict__ thresh) {
    double s = 0.0;
    for (int i = threadIdx.x; i < 1024; i += 256) s += (double)part[i];
    for (int off = 32; off; off >>= 1) s += __shfl_xor(s, off);
    __shared__ double red[4];
    if ((threadIdx.x & 63) == 0) red[threadIdx.x >> 6] = s;
    __syncthreads();
    if (threadIdx.x == 0) {
        double tot = red[0] + red[1] + red[2] + red[3];
        *thresh = (float)(0.5 * tot / 16777216.0);
    }
}

__global__ void quant_k(const float* __restrict__ w, const float* __restrict__ thresh,
                        signed char* __restrict__ q) {
    float t = *thresh;
    size_t i = ((size_t)blockIdx.x * 256 + threadIdx.x) * 4;
    if (i >= 16777216ull) return;
    float4 v = *(const float4*)(w + i);
    char4 o;
    o.x = (signed char)((v.x > t) - (v.x < -t));
    o.y = (signed char)((v.y > t) - (v.y < -t));
    o.z = (signed char)((v.z > t) - (v.z < -t));
    o.w = (signed char)((v.w > t) - (v.w < -t));
    *(char4*)(q + i) = o;
}

// ---------------- router + routing bookkeeping ----------------
__global__ __launch_bounds__(256) void router_k(const float* __restrict__ h2,
                                                const float* __restrict__ rw,
                                                int* __restrict__ topi, float* __restrict__ topw,
                                                int* __restrict__ counts, float* __restrict__ probsSum) {
    int wv = threadIdx.x >> 6, lane = threadIdx.x & 63;
    int t = blockIdx.x * 4 + wv;
    const float* hr = h2 + (size_t)t * kD;
    float part[8] = {};
    for (int i = 0; i < 16; i++) {
        int d = lane + (i << 6);
        float hv = hr[d];
#pragma unroll
        for (int e = 0; e < 8; e++) part[e] = fmaf(hv, rw[e * kD + d], part[e]);
    }
#pragma unroll
    for (int e = 0; e < 8; e++)
        for (int off = 32; off; off >>= 1) part[e] += __shfl_xor(part[e], off);
    float mx = part[0];
#pragma unroll
    for (int e = 1; e < 8; e++) mx = fmaxf(mx, part[e]);
    float p[8], sum = 0.f;
#pragma unroll
    for (int e = 0; e < 8; e++) { p[e] = expf(part[e] - mx); sum += p[e]; }
    float inv = 1.f / sum;
#pragma unroll
    for (int e = 0; e < 8; e++) p[e] *= inv;
    int i1 = 0; float p1 = p[0];
#pragma unroll
    for (int e = 1; e < 8; e++) if (p[e] > p1) { p1 = p[e]; i1 = e; }
    int i2 = -1; float p2 = -1.f;
#pragma unroll
    for (int e = 0; e < 8; e++) if (e != i1 && p[e] > p2) { p2 = p[e]; i2 = e; }
    if (lane == 0) {
        float wsum = p1 + p2 + 1e-9f;
        topi[2 * t] = i1; topi[2 * t + 1] = i2;
        topw[2 * t] = p1 / wsum; topw[2 * t + 1] = p2 / wsum;
        atomicAdd(&counts[i1], 1); atomicAdd(&counts[i2], 1);
#pragma unroll
        for (int e = 0; e < 8; e++) atomicAdd(&probsSum[e], p[e]);
    }
}

__global__ void route_offsets_k(const int* __restrict__ counts, int* offs, int* cursor,
                                int* pairTok, float* pairW, int* tileE, int* tileB, int* nTiles) {
    if (threadIdx.x != 0 || blockIdx.x != 0) return;
    int off = 0, tc = 0;
    for (int e = 0; e < 8; e++) {
        offs[e] = off; cursor[e] = off;
        int c = counts[e];
        int padded = (c + 63) & ~63;
        for (int p = c; p < padded; p++) { pairTok[off + p] = -1; pairW[off + p] = 0.f; }
        for (int j = 0; j < (padded >> 6); j++) { tileE[tc] = e; tileB[tc] = off + (j << 6); tc++; }
        off += padded;
    }
    offs[8] = off;
    *nTiles = tc;
    for (int j = tc; j < 80; j++) { tileE[j] = 0; tileB[j] = 0; }
}

__global__ void scatter_k(const int* __restrict__ topi, const float* __restrict__ topw,
                          int* cursor, int* pairTok, float* pairW) {
    int t = blockIdx.x * 256 + threadIdx.x;
    if (t >= kBT) return;
    for (int j = 0; j < 2; j++) {
        int e = topi[2 * t + j];
        int pos = atomicAdd(&cursor[e], 1);
        pairTok[pos] = t;
        pairW[pos] = topw[2 * t + j];
    }
}

// ---------------- MoE expert GEMMs (int8 ternary weights) ----------------
__global__ __launch_bounds__(256) void moe_gu(const float* __restrict__ h2,
                                              const signed char* __restrict__ qg,
                                              const signed char* __restrict__ qu,
                                              const float* __restrict__ gate_g,
                                              const float* __restrict__ up_g,
                                              const int* __restrict__ tileE, const int* __restrict__ tileB,
                                              const int* __restrict__ nTiles,
                                              const int* __restrict__ pairTok,
                                              float* __restrict__ hh) {
    if ((int)blockIdx.y >= *nTiles) return;
    int te = tileE[blockIdx.y], base = tileB[blockIdx.y];
    __shared__ __align__(16) float As[16][68], Bg[16][68], Bu[16][68];
    __shared__ int sTok[64];
    int tid = threadIdx.x;
    if (tid < 64) sTok[tid] = pairTok[base + tid];
    __syncthreads();
    int tx = tid & 15, ty = tid >> 4;
    int lr = tid >> 2, lk = (tid & 3) << 2;
    int n0 = blockIdx.x << 6;
    int tok = sTok[lr]; if (tok < 0) tok = 0;
    const float* Ap = h2 + (size_t)tok * kD + lk;
    const signed char* Gp = qg + ((size_t)te * kF + n0 + lr) * kD + lk;
    const signed char* Up = qu + ((size_t)te * kF + n0 + lr) * kD + lk;
    float accg[4][4] = {}, accu[4][4] = {};
    for (int kt = 0; kt < kD; kt += 16) {
        float4 a4 = *(const float4*)(Ap + kt);
        char4 g4 = *(const char4*)(Gp + kt);
        char4 u4 = *(const char4*)(Up + kt);
        __syncthreads();
        As[lk+0][lr] = a4.x; As[lk+1][lr] = a4.y; As[lk+2][lr] = a4.z; As[lk+3][lr] = a4.w;
        Bg[lk+0][lr] = (float)g4.x; Bg[lk+1][lr] = (float)g4.y; Bg[lk+2][lr] = (float)g4.z; Bg[lk+3][lr] = (float)g4.w;
        Bu[lk+0][lr] = (float)u4.x; Bu[lk+1][lr] = (float)u4.y; Bu[lk+2][lr] = (float)u4.z; Bu[lk+3][lr] = (float)u4.w;
        __syncthreads();
#pragma unroll
        for (int kk = 0; kk < 16; kk++) {
            float4 av = *(const float4*)&As[kk][ty << 2];
            float4 gv = *(const float4*)&Bg[kk][tx << 2];
            float4 uv = *(const float4*)&Bu[kk][tx << 2];
            float a_[4] = {av.x, av.y, av.z, av.w};
            float g_[4] = {gv.x, gv.y, gv.z, gv.w};
            float u_[4] = {uv.x, uv.y, uv.z, uv.w};
#pragma unroll
            for (int i = 0; i < 4; i++)
#pragma unroll
                for (int j = 0; j < 4; j++) {
                    accg[i][j] = fmaf(a_[i], g_[j], accg[i][j]);
                    accu[i][j] = fmaf(a_[i], u_[j], accu[i][j]);
                }
        }
    }
    float gs = gate_g[te], us = up_g[te];
#pragma unroll
    for (int i = 0; i < 4; i++) {
        float4 o;
        float* op = &o.x;
#pragma unroll
        for (int j = 0; j < 4; j++) {
            float g = accg[i][j] * gs, u = accu[i][j] * us;
            op[j] = g * sigmoidf_(g) * u;
        }
        *(float4*)(hh + (size_t)(base + (ty << 2) + i) * kF + n0 + (tx << 2)) = o;
    }
}

__global__ __launch_bounds__(256) void moe_down(const float* __restrict__ hh,
                                                const signed char* __restrict__ qd,
                                                const float* __restrict__ down_g,
                                                const int* __restrict__ tileE, const int* __restrict__ tileB,
                                                const int* __restrict__ nTiles,
                                                const int* __restrict__ pairTok, const float* __restrict__ pairW,
                                                float* __restrict__ out) {
    if ((int)blockIdx.y >= *nTiles) return;
    int te = tileE[blockIdx.y], base = tileB[blockIdx.y];
    __shared__ __align__(16) float As[16][68], Bs[16][68];
    __shared__ int sTok[64];
    __shared__ float sW[64];
    int tid = threadIdx.x;
    if (tid < 64) { sTok[tid] = pairTok[base + tid]; sW[tid] = pairW[base + tid]; }
    __syncthreads();
    int tx = tid & 15, ty = tid >> 4;
    int lr = tid >> 2, lk = (tid & 3) << 2;
    int n0 = blockIdx.x << 6;
    const float* Ap = hh + (size_t)(base + lr) * kF + lk;
    const signed char* Bp = qd + ((size_t)te * kD + n0 + lr) * kF + lk;
    float acc[4][4] = {};
    for (int kt = 0; kt < kF; kt += 16) {
        float4 a4 = *(const float4*)(Ap + kt);
        char4 b4 = *(const char4*)(Bp + kt);
        __syncthreads();
        As[lk+0][lr] = a4.x; As[lk+1][lr] = a4.y; As[lk+2][lr] = a4.z; As[lk+3][lr] = a4.w;
        Bs[lk+0][lr] = (float)b4.x; Bs[lk+1][lr] = (float)b4.y; Bs[lk+2][lr] = (float)b4.z; Bs[lk+3][lr] = (float)b4.w;
        __syncthreads();
#pragma unroll
        for (int kk = 0; kk < 16; kk++) {
            float4 av = *(const float4*)&As[kk][ty << 2];
            float4 bv = *(const float4*)&Bs[kk][tx << 2];
            float a_[4] = {av.x, av.y, av.z, av.w};
            float b_[4] = {bv.x, bv.y, bv.z, bv.w};
#pragma unroll
            for (int i = 0; i < 4; i++)
#pragma unroll
                for (int j = 0; j < 4; j++) acc[i][j] = fmaf(a_[i], b_[j], acc[i][j]);
        }
    }
    float ds = down_g[te];
#pragma unroll
    for (int i = 0; i < 4; i++) {
        int m = (ty << 2) + i;
        int tok = sTok[m];
        if (tok < 0) continue;
        float wv = sW[m] * ds;
#pragma unroll
        for (int j = 0; j < 4; j++)
            atomicAdd(&out[(size_t)tok * kD + n0 + (tx << 2) + j], acc[i][j] * wv);
    }
}

__global__ void aux_k(const float* __restrict__ probsSum, float* __restrict__ out) {
    if (threadIdx.x != 0 || blockIdx.x != 0) return;
    float ent = 0.f;
    for (int e = 0; e < 8; e++) {
        float p = probsSum[e] * (1.f / (float)kBT);
        ent -= p * logf(p + 1e-9f);
    }
    out[0] = -ent * 0.01f;
}

// ---------------- launch ----------------
extern "C" void kernel_launch(void* const* d_in, const int* in_sizes, int n_in,
                              void* d_out, int out_size, void* d_ws, size_t ws_size,
                              hipStream_t stream) {
    const float* x       = (const float*)d_in[0];
    const float* n1w     = (const float*)d_in[1];
    const float* n2w     = (const float*)d_in[2];
    const float* ssm_in_w= (const float*)d_in[3];
    const float* ssm_A_w = (const float*)d_in[4];
    const float* ssm_B_w = (const float*)d_in[5];
    const float* ssm_C_w = (const float*)d_in[6];
    const float* ssm_nw  = (const float*)d_in[7];
    const float* ssm_ow  = (const float*)d_in[8];
    const float* q_w     = (const float*)d_in[9];
    const float* kvd_w   = (const float*)d_in[10];
    const float* kup_w   = (const float*)d_in[11];
    const float* vup_w   = (const float*)d_in[12];
    const float* ao_w    = (const float*)d_in[13];
    const float* fuse_w  = (const float*)d_in[14];
    const float* rtr_w   = (const float*)d_in[15];
    const float* eg_w    = (const float*)d_in[16];
    const float* eu_w    = (const float*)d_in[17];
    const float* ed_w    = (const float*)d_in[18];
    const float* eg_g    = (const float*)d_in[19];
    const float* eu_g    = (const float*)d_in[20];
    const float* ed_g    = (const float*)d_in[21];
    float* out = (float*)d_out;
    float* wsf = (float*)d_ws;
    if (ws_size < WS_FLOATS * sizeof(float)) return;

    float* h      = wsf + F_H;
    float* hh     = wsf + F_HH;
    float* xin    = wsf + F_XIN;
    float* expA   = wsf + F_EXPA;
    float* cB     = wsf + F_CB;
    float* cC     = wsf + F_CC;
    float* Pv     = wsf + F_P;
    float* Qv     = wsf + F_Q;
    float* S0     = wsf + F_S0;
    float* ys     = wsf + F_YS;
    float* ssmo   = wsf + F_SSMO;
    float* attno  = wsf + F_ATTNO;
    float* h2     = wsf + F_H2;
    float* normed = wsf + F_NORMED;
    float* qb     = wsf + F_QB;
    float* kb     = wsf + F_KB;
    float* vb     = wsf + F_VB;
    float* lat    = wsf + F_LAT;
    float* ctx    = wsf + F_CTX;
    float* fuseb  = wsf + F_FUSE;
    float* xz     = wsf + F_XZ;
    float* scores = wsf + F_SCORES;
    signed char* qg = (signed char*)(wsf + F_QG8);
    signed char* qu = (signed char*)(wsf + F_QU8);
    signed char* qd = (signed char*)(wsf + F_QD8);
    float* part   = wsf + P_PART;
    float* thr    = wsf + P_THRESH;
    float* probs  = wsf + P_PROBS;
    int* counts   = (int*)(wsf + I_COUNTS);
    int* offs     = (int*)(wsf + I_OFFS);
    int* cursor   = (int*)(wsf + I_CURSOR);
    int* nTiles   = (int*)(wsf + I_NTILES);
    int* tileE    = (int*)(wsf + I_TILEE);
    int* tileB    = (int*)(wsf + I_TILEB);
    int* topi     = (int*)(wsf + I_TOPI);
    float* topw   = wsf + P_TOPW;
    int* pairT    = (int*)(wsf + I_PAIRT);
    float* pairW  = wsf + P_PAIRW;

    zero_k<<<1, 64, 0, stream>>>(wsf + P_PROBS, 34);
    // h = rmsnorm(x)
    rmsnorm_k<<<kBT, 256, 0, stream>>>(x, n1w, h, kD);
    // SSM branch
    gemm_nt<<<dim3(64, 32, 1), 256, 0, stream>>>(h, ssm_in_w, xz, 1024, 1024, 1024, 4096, 1, 0, 0, 0, 0, 0, 0);
    glu_k<<<(kBT * kDI / 4) / 256, 256, 0, stream>>>(xz, xin);
    projabc_k<<<kBT, 256, 0, stream>>>(xin, ssm_A_w, ssm_B_w, ssm_C_w, expA, cB, cC);
    scan_pass1<<<dim3(16, 16, 1), 256, 0, stream>>>(xin, expA, cB, Pv, Qv);
    scan_combine<<<16, 256, 0, stream>>>(Pv, Qv, S0);
    scan_pass2<<<dim3(16, 16, 1), 256, 0, stream>>>(xin, expA, cB, cC, S0, ys);
    rmsnorm_k<<<kBT, 256, 0, stream>>>(ys, ssm_nw, normed, kDI);
    gemm_nt<<<dim3(16, 32, 1), 256, 0, stream>>>(normed, ssm_ow, ssmo, 2048, 2048, 2048, 1024, 1, 0, 0, 0, 0, 0, 0);
    // MLA attention
    gemm_nt<<<dim3(16, 32, 1), 256, 0, stream>>>(h, q_w, qb, 1024, 1024, 1024, 1024, 1, 0, 0, 0, 0, 0, 0);
    gemm_nt<<<dim3(4, 32, 1), 256, 0, stream>>>(h, kvd_w, lat, 1024, 1024, 1024, 256, 1, 0, 0, 0, 0, 0, 0);
    gemm_nt<<<dim3(16, 32, 1), 256, 0, stream>>>(lat, kup_w, kb, 256, 256, 256, 1024, 1, 0, 0, 0, 0, 0, 0);
    gemm_nt<<<dim3(16, 32, 1), 256, 0, stream>>>(lat, vup_w, vb, 256, 256, 256, 1024, 1, 0, 0, 0, 0, 0, 0);
    for (int b = 0; b < 2; b++) {
        const float* qp = qb + (size_t)b * kT * kD;
        const float* kp = kb + (size_t)b * kT * kD;
        const float* vp = vb + (size_t)b * kT * kD;
        float* ctxp = ctx + (size_t)b * kT * kD;
        gemm_nt<<<dim3(16, 16, 16), 256, 0, stream>>>(qp, kp, scores, 64, 1024, 1024, 1024,
                                                      16, 0, 64, 0, 64, 0, (long)kT * kT);
        softmax_rows<<<kH * kT, 256, 0, stream>>>(scores);
        gemm_nn<<<dim3(1, 16, 16), 256, 0, stream>>>(scores, vp, ctxp, 1024, 1024, 1024, 1024,
                                                     16, 0, (long)kT * kT, 0, 64, 0, 64);
    }
    gemm_nt<<<dim3(16, 32, 1), 256, 0, stream>>>(ctx, ao_w, attno, 1024, 1024, 1024, 1024, 1, 0, 0, 0, 0, 0, 0);
    // gated fuse
    gemm_nt<<<dim3(16, 32, 1), 256, 0, stream>>>(h, fuse_w, fuseb, 1024, 1024, 1024, 1024, 1, 0, 0, 0, 0, 0, 0);
    fuse_k<<<(kBT * kD / 4) / 256, 256, 0, stream>>>(x, fuseb, ssmo, attno, out);
    // rmsnorm2
    rmsnorm_k<<<kBT, 256, 0, stream>>>(out, n2w, h2, kD);
    // ternary quantization of MoE weights
    const float* wsrc[3] = {eg_w, eu_w, ed_w};
    signed char* qdst[3] = {qg, qu, qd};
    for (int i = 0; i < 3; i++) {
        absmean_partial<<<1024, 256, 0, stream>>>(wsrc[i], part + i * 1024);
        thresh_k<<<1, 256, 0, stream>>>(part + i * 1024, thr + i);
        quant_k<<<16384, 256, 0, stream>>>(wsrc[i], thr + i, qdst[i]);
    }
    // routing
    router_k<<<kBT / 4, 256, 0, stream>>>(h2, rtr_w, topi, topw, counts, probs);
    route_offsets_k<<<1, 64, 0, stream>>>(counts, offs, cursor, pairT, pairW, tileE, tileB, nTiles);
    scatter_k<<<kBT / 256, 256, 0, stream>>>(topi, topw, cursor, pairT, pairW);
    // expert GEMMs (top-2 only, padded tiles; extra tiles early-exit on nTiles)
    moe_gu<<<dim3(kF / 64, 72, 1), 256, 0, stream>>>(h2, qg, qu, eg_g, eu_g, tileE, tileB, nTiles, pairT, hh);
    moe_down<<<dim3(kD / 64, 72, 1), 256, 0, stream>>>(hh, qd, ed_g, tileE, tileB, nTiles, pairT, pairW, out);
    aux_k<<<1, 64, 0, stream>>>(probs, out + (size_t)kBT * kD);
}